// Round 5
// baseline (163.092 us; speedup 1.0000x reference)
//
#include <hip/hip_runtime.h>
#include <hip/hip_bf16.h>

// B=2, T=2048, C=768, H=12, D=64. 3C=2304. BT=4096.
// prologue (cast + weight transposes); QKV GEMM 128x128 reg-prefetch ->
// Q,K row-major + V transposed [b][h][d][t]; causal flash attention SPLIT-K2
// (fixed-max softmax => linear partials; f32 acc/psum slots per chunk);
// proj GEMM 64x128 reg-prefetch with fused partial-combine A-staging -> fp32 out.

using half4   = __attribute__((ext_vector_type(4))) _Float16;
using half8   = __attribute__((ext_vector_type(8))) _Float16;
using floatx4 = __attribute__((ext_vector_type(4))) float;

#define T_SEQ 2048
#define NHEAD 12
#define HDIM 64
#define C3 2304
#define CDIM 768
#define BT 4096
#define BH 24          // B * NHEAD

static __device__ inline _Float16 f2h(float f) { return (_Float16)f; }

// ---------------- fused prologue: weight transposes + x cast ----------------
__global__ __launch_bounds__(256)
void prologue(const float* __restrict__ x, const float* __restrict__ wa,
              const float* __restrict__ wp, _Float16* __restrict__ xb,
              _Float16* __restrict__ wTa, _Float16* __restrict__ wTp) {
    __shared__ float tile[32][33];
    int blk = blockIdx.x, tid = threadIdx.x;
    if (blk < 2304) {
        const float* w; _Float16* wT; int K, N, bx, by;
        if (blk < 1728) { w = wa; wT = wTa; K = CDIM; N = C3; bx = blk % 72; by = blk / 72; }
        else { int b2 = blk - 1728; w = wp; wT = wTp; K = CDIM; N = CDIM; bx = b2 % 24; by = b2 / 24; }
        int tx = tid & 31, ty = tid >> 5;
        #pragma unroll
        for (int j = 0; j < 32; j += 8) {
            int k = by * 32 + ty + j, n = bx * 32 + tx;
            tile[ty + j][tx] = w[(long)k * N + n];
        }
        __syncthreads();
        #pragma unroll
        for (int j = 0; j < 32; j += 8) {
            int nO = bx * 32 + ty + j, kO = by * 32 + tx;
            wT[(long)nO * K + kO] = f2h(tile[tx][ty + j]);
        }
    } else {
        int b2 = blk - 2304;
        long base = (long)b2 * 1536;
        #pragma unroll
        for (int j = 0; j < 6; ++j) {
            long i = base + j * 256 + tid;
            xb[i] = f2h(x[i]);
        }
    }
}

// ---------------- QKV GEMM: 128x128 tile, BK=32, register-prefetch ----------
__global__ __launch_bounds__(256)
void gemm_qkv(const _Float16* __restrict__ A, const _Float16* __restrict__ Bt,
              const float* __restrict__ bias,
              _Float16* __restrict__ Qb, _Float16* __restrict__ Kb,
              _Float16* __restrict__ Vt) {
    __shared__ __align__(16) _Float16 As[128 * 32];
    __shared__ __align__(16) _Float16 Bs[128 * 32];
    const int K = CDIM;
    int tid = threadIdx.x;
    int m0 = blockIdx.x * 128, n0 = blockIdx.y * 128;
    int w = tid >> 6, l = tid & 63;
    int wm = (w >> 1) * 64, wn = (w & 1) * 64;
    int lr = l & 15, lq = l >> 4;

    int ea0 = tid * 8, ea1 = (256 + tid) * 8;
    int ra0 = ea0 >> 5, ca0 = ea0 & 31, ra1 = ea1 >> 5, ca1 = ea1 & 31;

    floatx4 acc[4][4] = {};

    half8 Ar0 = *(const half8*)&A[(long)(m0 + ra0) * K + ca0];
    half8 Ar1 = *(const half8*)&A[(long)(m0 + ra1) * K + ca1];
    half8 Br0 = *(const half8*)&Bt[(long)(n0 + ra0) * K + ca0];
    half8 Br1 = *(const half8*)&Bt[(long)(n0 + ra1) * K + ca1];

    for (int kb = 0; kb < K; kb += 32) {
        *(half8*)&As[ea0] = Ar0;
        *(half8*)&As[ea1] = Ar1;
        *(half8*)&Bs[ea0] = Br0;
        *(half8*)&Bs[ea1] = Br1;
        __syncthreads();
        if (kb + 32 < K) {
            Ar0 = *(const half8*)&A[(long)(m0 + ra0) * K + kb + 32 + ca0];
            Ar1 = *(const half8*)&A[(long)(m0 + ra1) * K + kb + 32 + ca1];
            Br0 = *(const half8*)&Bt[(long)(n0 + ra0) * K + kb + 32 + ca0];
            Br1 = *(const half8*)&Bt[(long)(n0 + ra1) * K + kb + 32 + ca1];
        }
        half8 af[4], bf[4];
        #pragma unroll
        for (int i = 0; i < 4; ++i) {
            af[i] = *(const half8*)&As[(wm + i * 16 + lr) * 32 + lq * 8];
            bf[i] = *(const half8*)&Bs[(wn + i * 16 + lr) * 32 + lq * 8];
        }
        #pragma unroll
        for (int mi = 0; mi < 4; ++mi)
            #pragma unroll
            for (int ni = 0; ni < 4; ++ni)
                acc[mi][ni] = __builtin_amdgcn_mfma_f32_16x16x32_f16(af[mi], bf[ni], acc[mi][ni], 0, 0, 0);
        __syncthreads();
    }

    int region = n0 / CDIM;   // by 0-5 Q, 6-11 K, 12-17 V
    if (region < 2) {
        _Float16* O = region ? Kb : Qb;
        int nc0 = n0 - region * CDIM + wn;
        #pragma unroll
        for (int mi = 0; mi < 4; ++mi)
            #pragma unroll
            for (int ni = 0; ni < 4; ++ni) {
                int col = nc0 + ni * 16 + lr;
                float bsc = bias[region * CDIM + col];
                #pragma unroll
                for (int r = 0; r < 4; ++r) {
                    int row = m0 + wm + mi * 16 + lq * 4 + r;
                    O[(long)row * CDIM + col] = f2h(acc[mi][ni][r] + bsc);
                }
            }
    } else {
        #pragma unroll
        for (int mi = 0; mi < 4; ++mi)
            #pragma unroll
            for (int ni = 0; ni < 4; ++ni) {
                int cv = n0 - 2 * CDIM + wn + ni * 16 + lr;    // 0..767
                float bsc = bias[2 * CDIM + cv];
                int h = cv >> 6, d = cv & 63;
                int t0 = m0 + wm + mi * 16 + lq * 4;
                int bb = t0 >> 11, t = t0 & 2047;
                half4 hv;
                #pragma unroll
                for (int r = 0; r < 4; ++r) hv[r] = f2h(acc[mi][ni][r] + bsc);
                *(half4*)&Vt[(((long)bb * NHEAD + h) * HDIM + d) * T_SEQ + t] = hv;
            }
    }
}

// ---------------- causal flash attention, split-K2, partial outputs ----------
// Q,K: [b][t][h*64+d] f16. Vt: [b][h][d][t] f16.
// Pacc[chunk][bh][t][d] f32, Ppsum[chunk][bh][t] f32.
// Grid 1536: blk -> chunk = blk&1; rest: bh = rest%24, qb = 31 - rest/24.
__global__ __launch_bounds__(256)
void attn_kernel(const _Float16* __restrict__ Qb, const _Float16* __restrict__ Kb,
                 const _Float16* __restrict__ Vt,
                 float* __restrict__ Pacc, float* __restrict__ Ppsum) {
    __shared__ __align__(16) _Float16 Ks[64 * 72];
    __shared__ __align__(16) _Float16 Vs[64 * 72];
    __shared__ __align__(16) _Float16 Ps[4][16 * 72];
    int tid = threadIdx.x;
    int w = tid >> 6, l = tid & 63;
    int lr = l & 15, lq = l >> 4;
    int blk = blockIdx.x;
    int chunk = blk & 1;
    int rest = blk >> 1;
    int bh = rest % BH;
    int qb = 31 - rest / BH;               // heavy q-tiles first, chunks interleaved
    int b = bh / NHEAD, h = bh % NHEAD;
    int q0 = qb * 64 + w * 16;

    int lo = chunk ? ((qb + 1) >> 1) : 0;
    int hi = chunk ? (qb + 1) : ((qb + 1) >> 1);

    const _Float16* Qp = Qb + (long)b * T_SEQ * CDIM + h * HDIM;
    const _Float16* Kg = Kb + (long)b * T_SEQ * CDIM + h * HDIM;
    const _Float16* Vg = Vt + (long)bh * HDIM * T_SEQ;

    int r0 = tid >> 3, c0 = (tid & 7) * 8;
    int r1 = r0 + 32;

    const float qscale = 0.125f * 1.44269504f;
    half8 aq[2];
    #pragma unroll
    for (int kk = 0; kk < 2; ++kk) {
        aq[kk] = *(const half8*)&Qp[(long)(q0 + lr) * CDIM + kk * 32 + lq * 8];
        #pragma unroll
        for (int j = 0; j < 8; ++j) aq[kk][j] = f2h((float)aq[kk][j] * qscale);
    }

    // prefetch first tile of this chunk (valid addresses even if range empty)
    int kb0 = lo * 64;
    half8 Kr0 = *(const half8*)&Kg[(long)(kb0 + r0) * CDIM + c0];
    half8 Kr1 = *(const half8*)&Kg[(long)(kb0 + r1) * CDIM + c0];
    half8 Vr0 = *(const half8*)&Vg[(long)r0 * T_SEQ + kb0 + c0];
    half8 Vr1 = *(const half8*)&Vg[(long)r1 * T_SEQ + kb0 + c0];

    float psum[4] = {0.f, 0.f, 0.f, 0.f};
    floatx4 acc[4] = {};

    for (int kt = lo; kt < hi; ++kt) {
        int kbase = kt * 64;
        *(half8*)&Ks[r0 * 72 + c0] = Kr0;
        *(half8*)&Ks[r1 * 72 + c0] = Kr1;
        *(half8*)&Vs[r0 * 72 + c0] = Vr0;
        *(half8*)&Vs[r1 * 72 + c0] = Vr1;
        __syncthreads();
        if (kt + 1 < hi) {
            int nb = kbase + 64;
            Kr0 = *(const half8*)&Kg[(long)(nb + r0) * CDIM + c0];
            Kr1 = *(const half8*)&Kg[(long)(nb + r1) * CDIM + c0];
            Vr0 = *(const half8*)&Vg[(long)r0 * T_SEQ + nb + c0];
            Vr1 = *(const half8*)&Vg[(long)r1 * T_SEQ + nb + c0];
        }

        floatx4 sacc[4] = {};
        #pragma unroll
        for (int s = 0; s < 4; ++s)
            #pragma unroll
            for (int kk = 0; kk < 2; ++kk) {
                half8 bk = *(const half8*)&Ks[(s * 16 + lr) * 72 + kk * 32 + lq * 8];
                sacc[s] = __builtin_amdgcn_mfma_f32_16x16x32_f16(aq[kk], bk, sacc[s], 0, 0, 0);
            }

        if (kt == qb) {   // diagonal tile (always in chunk 1)
            #pragma unroll
            for (int r = 0; r < 4; ++r) {
                int row = q0 + lq * 4 + r;
                #pragma unroll
                for (int s = 0; s < 4; ++s) {
                    float p = (kbase + s * 16 + lr > row) ? 0.f
                              : __builtin_amdgcn_exp2f(sacc[s][r]);
                    psum[r] += p;
                    Ps[w][(lq * 4 + r) * 72 + s * 16 + lr] = f2h(p);
                }
            }
        } else {
            #pragma unroll
            for (int r = 0; r < 4; ++r) {
                #pragma unroll
                for (int s = 0; s < 4; ++s) {
                    float p = __builtin_amdgcn_exp2f(sacc[s][r]);
                    psum[r] += p;
                    Ps[w][(lq * 4 + r) * 72 + s * 16 + lr] = f2h(p);
                }
            }
        }

        half8 ap0 = *(const half8*)&Ps[w][lr * 72 + lq * 8];
        half8 ap1 = *(const half8*)&Ps[w][lr * 72 + 32 + lq * 8];
        #pragma unroll
        for (int n = 0; n < 4; ++n) {
            #pragma unroll
            for (int kk = 0; kk < 2; ++kk) {
                half8 bv = *(const half8*)&Vs[(n * 16 + lr) * 72 + kk * 32 + lq * 8];
                acc[n] = __builtin_amdgcn_mfma_f32_16x16x32_f16(kk ? ap1 : ap0, bv, acc[n], 0, 0, 0);
            }
        }
        __syncthreads();
    }

    // reduce psum across the 16 lanes per row; write partials unconditionally
    float* accb = Pacc + ((long)(chunk * BH + bh) * T_SEQ) * HDIM;
    float* psb  = Ppsum + (long)(chunk * BH + bh) * T_SEQ;
    #pragma unroll
    for (int r = 0; r < 4; ++r) {
        float s = psum[r];
        #pragma unroll
        for (int off = 1; off < 16; off <<= 1)
            s += __shfl_xor(s, off, 64);
        if (lr == 0) psb[q0 + lq * 4 + r] = s;
    }
    #pragma unroll
    for (int n = 0; n < 4; ++n)
        #pragma unroll
        for (int r = 0; r < 4; ++r)
            accb[(long)(q0 + lq * 4 + r) * HDIM + n * 16 + lr] = acc[n][r];
}

// ---------------- proj GEMM: 64x128, reg-prefetch, fused partial combine -----
// A = (Pacc0+Pacc1)/(psum0+psum1) cast f16 on the fly. Bt = wTp. fp32 out + bias.
__global__ __launch_bounds__(256)
void gemm_proj(const float* __restrict__ Pacc, const float* __restrict__ Ppsum,
               const _Float16* __restrict__ Bt,
               const float* __restrict__ bias, float* __restrict__ Cout) {
    __shared__ __align__(16) _Float16 As[64 * 32];
    __shared__ __align__(16) _Float16 Bs[128 * 32];
    const int K = CDIM, N = CDIM;
    const long CH = (long)BH * T_SEQ * HDIM;   // chunk stride in Pacc
    int tid = threadIdx.x;
    int m0 = blockIdx.x * 64, n0 = blockIdx.y * 128;
    int w = tid >> 6, l = tid & 63;
    int wm = (w >> 1) * 32, wn = (w & 1) * 64;
    int lr = l & 15, lq = l >> 4;

    int e = tid * 8, re = e >> 5, ce = e & 31;
    int eb0 = tid * 8, eb1 = (256 + tid) * 8;
    int rb0 = eb0 >> 5, cb0 = eb0 & 31, rb1 = eb1 >> 5, cb1 = eb1 & 31;

    // token for A staging
    int t = m0 + re;
    int bb = t >> 11, tl = t & 2047;
    float l0 = Ppsum[((long)bb * NHEAD) * T_SEQ + 0];   // placeholder init (overwritten)
    floatx4 acc[2][4] = {};

    // A-prefetch for kb=0
    int gc = ce;                      // global col (kb + ce)
    int hh = gc >> 6, dd = gc & 63;
    const float* s0 = Pacc + ((long)(bb * NHEAD + hh) * T_SEQ + tl) * HDIM + dd;
    floatx4 Aa0 = *(const floatx4*)s0;
    floatx4 Aa1 = *(const floatx4*)(s0 + 4);
    floatx4 Ab0 = *(const floatx4*)(s0 + CH);
    floatx4 Ab1 = *(const floatx4*)(s0 + CH + 4);
    l0 = Ppsum[(long)(bb * NHEAD + hh) * T_SEQ + tl];
    float l1 = Ppsum[(long)(BH + bb * NHEAD + hh) * T_SEQ + tl];

    half8 Br0 = *(const half8*)&Bt[(long)(n0 + rb0) * K + cb0];
    half8 Br1 = *(const half8*)&Bt[(long)(n0 + rb1) * K + cb1];

    for (int kb = 0; kb < K; kb += 32) {
        {
            float rc = __builtin_amdgcn_rcpf(l0 + l1);
            half8 h8;
            #pragma unroll
            for (int j = 0; j < 4; ++j) {
                h8[j]     = f2h((Aa0[j] + Ab0[j]) * rc);
                h8[4 + j] = f2h((Aa1[j] + Ab1[j]) * rc);
            }
            *(half8*)&As[e] = h8;
        }
        *(half8*)&Bs[eb0] = Br0;
        *(half8*)&Bs[eb1] = Br1;
        __syncthreads();
        if (kb + 32 < K) {
            gc = kb + 32 + ce;
            hh = gc >> 6; dd = gc & 63;
            s0 = Pacc + ((long)(bb * NHEAD + hh) * T_SEQ + tl) * HDIM + dd;
            Aa0 = *(const floatx4*)s0;
            Aa1 = *(const floatx4*)(s0 + 4);
            Ab0 = *(const floatx4*)(s0 + CH);
            Ab1 = *(const floatx4*)(s0 + CH + 4);
            l0 = Ppsum[(long)(bb * NHEAD + hh) * T_SEQ + tl];
            l1 = Ppsum[(long)(BH + bb * NHEAD + hh) * T_SEQ + tl];
            Br0 = *(const half8*)&Bt[(long)(n0 + rb0) * K + kb + 32 + cb0];
            Br1 = *(const half8*)&Bt[(long)(n0 + rb1) * K + kb + 32 + cb1];
        }
        half8 af[2], bf[4];
        #pragma unroll
        for (int i = 0; i < 2; ++i)
            af[i] = *(const half8*)&As[(wm + i * 16 + lr) * 32 + lq * 8];
        #pragma unroll
        for (int i = 0; i < 4; ++i)
            bf[i] = *(const half8*)&Bs[(wn + i * 16 + lr) * 32 + lq * 8];
        #pragma unroll
        for (int mi = 0; mi < 2; ++mi)
            #pragma unroll
            for (int ni = 0; ni < 4; ++ni)
                acc[mi][ni] = __builtin_amdgcn_mfma_f32_16x16x32_f16(af[mi], bf[ni], acc[mi][ni], 0, 0, 0);
        __syncthreads();
    }
    #pragma unroll
    for (int mi = 0; mi < 2; ++mi)
        #pragma unroll
        for (int ni = 0; ni < 4; ++ni) {
            int col = n0 + wn + ni * 16 + lr;
            float b = bias[col];
            #pragma unroll
            for (int r = 0; r < 4; ++r) {
                int row = m0 + wm + mi * 16 + lq * 4 + r;
                Cout[(long)row * N + col] = acc[mi][ni][r] + b;
            }
        }
}

extern "C" void kernel_launch(void* const* d_in, const int* in_sizes, int n_in,
                              void* d_out, int out_size, void* d_ws, size_t ws_size,
                              hipStream_t stream) {
    const float* x      = (const float*)d_in[0];
    const float* w_attn = (const float*)d_in[1];
    const float* b_attn = (const float*)d_in[2];
    const float* w_proj = (const float*)d_in[3];
    const float* b_proj = (const float*)d_in[4];
    float* out = (float*)d_out;

    char* ws = (char*)d_ws;
    _Float16* xb   = (_Float16*)(ws);               // 6,291,456
    _Float16* wTa  = (_Float16*)(ws + 6291456);     // 3,538,944
    _Float16* wTp  = (_Float16*)(ws + 9830400);     // 1,179,648
    _Float16* Qb   = (_Float16*)(ws + 11010048);    // 6,291,456
    _Float16* Kb   = (_Float16*)(ws + 17301504);    // 6,291,456
    _Float16* Vt   = (_Float16*)(ws + 23592960);    // 6,291,456
    float*    Pacc = (float*)(ws + 29884416);       // 25,165,824
    float*    Ppsum= (float*)(ws + 55050240);       // 393,216
    // total 55,443,456 B

    prologue<<<4352, 256, 0, stream>>>(x, w_attn, w_proj, xb, wTa, wTp);

    gemm_qkv<<<dim3(BT / 128, C3 / 128), 256, 0, stream>>>(xb, wTa, b_attn, Qb, Kb, Vt);

    attn_kernel<<<2 * BH * (T_SEQ / 64), 256, 0, stream>>>(Qb, Kb, Vt, Pacc, Ppsum);

    gemm_proj<<<dim3(BT / 64, CDIM / 128), 256, 0, stream>>>(Pacc, Ppsum, wTp, b_proj, out);
}

// Round 6
// 152.630 us; speedup vs baseline: 1.0685x; 1.0685x over previous
//
#include <hip/hip_runtime.h>
#include <hip/hip_bf16.h>

// B=2, T=2048, C=768, H=12, D=64. 3C=2304. BT=4096.
// prologue (cast + weight transposes); QKV GEMM 128x64 BK=64 reg-prefetch ->
// Q,K row-major + V transposed [b][h][d][t]; causal flash attention with
// 128-key LDS tiles, fixed-max softmax, reg-prefetch; proj GEMM 64x128 BK=64.

using half4   = __attribute__((ext_vector_type(4))) _Float16;
using half8   = __attribute__((ext_vector_type(8))) _Float16;
using floatx4 = __attribute__((ext_vector_type(4))) float;

#define T_SEQ 2048
#define NHEAD 12
#define HDIM 64
#define C3 2304
#define CDIM 768
#define BT 4096
#define BH 24

static __device__ inline _Float16 f2h(float f) { return (_Float16)f; }

// ---------------- fused prologue: weight transposes + x cast ----------------
__global__ __launch_bounds__(256)
void prologue(const float* __restrict__ x, const float* __restrict__ wa,
              const float* __restrict__ wp, _Float16* __restrict__ xb,
              _Float16* __restrict__ wTa, _Float16* __restrict__ wTp) {
    __shared__ float tile[32][33];
    int blk = blockIdx.x, tid = threadIdx.x;
    if (blk < 2304) {
        const float* w; _Float16* wT; int K, N, bx, by;
        if (blk < 1728) { w = wa; wT = wTa; K = CDIM; N = C3; bx = blk % 72; by = blk / 72; }
        else { int b2 = blk - 1728; w = wp; wT = wTp; K = CDIM; N = CDIM; bx = b2 % 24; by = b2 / 24; }
        int tx = tid & 31, ty = tid >> 5;
        #pragma unroll
        for (int j = 0; j < 32; j += 8) {
            int k = by * 32 + ty + j, n = bx * 32 + tx;
            tile[ty + j][tx] = w[(long)k * N + n];
        }
        __syncthreads();
        #pragma unroll
        for (int j = 0; j < 32; j += 8) {
            int nO = bx * 32 + ty + j, kO = by * 32 + tx;
            wT[(long)nO * K + kO] = f2h(tile[tx][ty + j]);
        }
    } else {
        int b2 = blk - 2304;
        long base = (long)b2 * 1536;
        #pragma unroll
        for (int j = 0; j < 6; ++j) {
            long i = base + j * 256 + tid;
            xb[i] = f2h(x[i]);
        }
    }
}

// ---------------- QKV GEMM: 128x64 tile, BK=64, register-prefetch ------------
// A[4096][768] f16, Bt[2304][768] f16. Writes Q,K row-major; V -> Vt[b][h][d][t].
__global__ __launch_bounds__(256)
void gemm_qkv(const _Float16* __restrict__ A, const _Float16* __restrict__ Bt,
              const float* __restrict__ bias,
              _Float16* __restrict__ Qb, _Float16* __restrict__ Kb,
              _Float16* __restrict__ Vt) {
    __shared__ __align__(16) _Float16 As[128 * 72];
    __shared__ __align__(16) _Float16 Bs[64 * 72];
    const int K = CDIM;
    int tid = threadIdx.x;
    int m0 = blockIdx.x * 128, n0 = blockIdx.y * 64;
    int w = tid >> 6, l = tid & 63;
    int wm = (w >> 1) * 64, wn = (w & 1) * 32;
    int lr = l & 15, lq = l >> 4;

    // staging coords: element e = (j*256+tid)*8 within [rows][64]
    int rs = tid >> 3, cs = (tid & 7) * 8;   // row step 32 per j

    floatx4 acc[4][2] = {};

    half8 Ar[4], Br[2];
    #pragma unroll
    for (int j = 0; j < 4; ++j)
        Ar[j] = *(const half8*)&A[(long)(m0 + j * 32 + rs) * K + cs];
    #pragma unroll
    for (int j = 0; j < 2; ++j)
        Br[j] = *(const half8*)&Bt[(long)(n0 + j * 32 + rs) * K + cs];

    for (int kb = 0; kb < K; kb += 64) {
        #pragma unroll
        for (int j = 0; j < 4; ++j)
            *(half8*)&As[(j * 32 + rs) * 72 + cs] = Ar[j];
        #pragma unroll
        for (int j = 0; j < 2; ++j)
            *(half8*)&Bs[(j * 32 + rs) * 72 + cs] = Br[j];
        __syncthreads();
        if (kb + 64 < K) {
            #pragma unroll
            for (int j = 0; j < 4; ++j)
                Ar[j] = *(const half8*)&A[(long)(m0 + j * 32 + rs) * K + kb + 64 + cs];
            #pragma unroll
            for (int j = 0; j < 2; ++j)
                Br[j] = *(const half8*)&Bt[(long)(n0 + j * 32 + rs) * K + kb + 64 + cs];
        }
        #pragma unroll
        for (int kh = 0; kh < 2; ++kh) {
            half8 af[4], bf[2];
            #pragma unroll
            for (int i = 0; i < 4; ++i)
                af[i] = *(const half8*)&As[(wm + i * 16 + lr) * 72 + kh * 32 + lq * 8];
            #pragma unroll
            for (int i = 0; i < 2; ++i)
                bf[i] = *(const half8*)&Bs[(wn + i * 16 + lr) * 72 + kh * 32 + lq * 8];
            #pragma unroll
            for (int mi = 0; mi < 4; ++mi)
                #pragma unroll
                for (int ni = 0; ni < 2; ++ni)
                    acc[mi][ni] = __builtin_amdgcn_mfma_f32_16x16x32_f16(af[mi], bf[ni], acc[mi][ni], 0, 0, 0);
        }
        __syncthreads();
    }

    int region = n0 / CDIM;   // n0 in units of 64: 0-11 Q, 12-23 K, 24-35 V
    if (region < 2) {
        _Float16* O = region ? Kb : Qb;
        int nc0 = n0 - region * CDIM + wn;
        #pragma unroll
        for (int mi = 0; mi < 4; ++mi)
            #pragma unroll
            for (int ni = 0; ni < 2; ++ni) {
                int col = nc0 + ni * 16 + lr;
                float bsc = bias[region * CDIM + col];
                #pragma unroll
                for (int r = 0; r < 4; ++r) {
                    int row = m0 + wm + mi * 16 + lq * 4 + r;
                    O[(long)row * CDIM + col] = f2h(acc[mi][ni][r] + bsc);
                }
            }
    } else {
        #pragma unroll
        for (int mi = 0; mi < 4; ++mi)
            #pragma unroll
            for (int ni = 0; ni < 2; ++ni) {
                int cv = n0 - 2 * CDIM + wn + ni * 16 + lr;    // 0..767
                float bsc = bias[2 * CDIM + cv];
                int h = cv >> 6, d = cv & 63;
                int t0 = m0 + wm + mi * 16 + lq * 4;
                int bb = t0 >> 11, t = t0 & 2047;
                half4 hv;
                #pragma unroll
                for (int r = 0; r < 4; ++r) hv[r] = f2h(acc[mi][ni][r] + bsc);
                *(half4*)&Vt[(((long)bb * NHEAD + h) * HDIM + d) * T_SEQ + t] = hv;
            }
    }
}

// ---------------- proj GEMM: 64x128 tile, BK=64, reg-prefetch, fp32 out ------
__global__ __launch_bounds__(256)
void gemm_proj(const _Float16* __restrict__ A, const _Float16* __restrict__ Bt,
               const float* __restrict__ bias, float* __restrict__ Cout) {
    __shared__ __align__(16) _Float16 As[64 * 72];
    __shared__ __align__(16) _Float16 Bs[128 * 72];
    const int K = CDIM, N = CDIM;
    int tid = threadIdx.x;
    int m0 = blockIdx.x * 64, n0 = blockIdx.y * 128;
    int w = tid >> 6, l = tid & 63;
    int wm = (w >> 1) * 32, wn = (w & 1) * 64;
    int lr = l & 15, lq = l >> 4;

    int rs = tid >> 3, cs = (tid & 7) * 8;

    floatx4 acc[2][4] = {};

    half8 Ar[2], Br[4];
    #pragma unroll
    for (int j = 0; j < 2; ++j)
        Ar[j] = *(const half8*)&A[(long)(m0 + j * 32 + rs) * K + cs];
    #pragma unroll
    for (int j = 0; j < 4; ++j)
        Br[j] = *(const half8*)&Bt[(long)(n0 + j * 32 + rs) * K + cs];

    for (int kb = 0; kb < K; kb += 64) {
        #pragma unroll
        for (int j = 0; j < 2; ++j)
            *(half8*)&As[(j * 32 + rs) * 72 + cs] = Ar[j];
        #pragma unroll
        for (int j = 0; j < 4; ++j)
            *(half8*)&Bs[(j * 32 + rs) * 72 + cs] = Br[j];
        __syncthreads();
        if (kb + 64 < K) {
            #pragma unroll
            for (int j = 0; j < 2; ++j)
                Ar[j] = *(const half8*)&A[(long)(m0 + j * 32 + rs) * K + kb + 64 + cs];
            #pragma unroll
            for (int j = 0; j < 4; ++j)
                Br[j] = *(const half8*)&Bt[(long)(n0 + j * 32 + rs) * K + kb + 64 + cs];
        }
        #pragma unroll
        for (int kh = 0; kh < 2; ++kh) {
            half8 af[2], bf[4];
            #pragma unroll
            for (int i = 0; i < 2; ++i)
                af[i] = *(const half8*)&As[(wm + i * 16 + lr) * 72 + kh * 32 + lq * 8];
            #pragma unroll
            for (int i = 0; i < 4; ++i)
                bf[i] = *(const half8*)&Bs[(wn + i * 16 + lr) * 72 + kh * 32 + lq * 8];
            #pragma unroll
            for (int mi = 0; mi < 2; ++mi)
                #pragma unroll
                for (int ni = 0; ni < 4; ++ni)
                    acc[mi][ni] = __builtin_amdgcn_mfma_f32_16x16x32_f16(af[mi], bf[ni], acc[mi][ni], 0, 0, 0);
        }
        __syncthreads();
    }
    #pragma unroll
    for (int mi = 0; mi < 2; ++mi)
        #pragma unroll
        for (int ni = 0; ni < 4; ++ni) {
            int col = n0 + wn + ni * 16 + lr;
            float b = bias[col];
            #pragma unroll
            for (int r = 0; r < 4; ++r) {
                int row = m0 + wm + mi * 16 + lq * 4 + r;
                Cout[(long)row * N + col] = acc[mi][ni][r] + b;
            }
        }
}

// ---------------- causal flash attention, 128-key tiles, reg-prefetch --------
// Q,K: [b][t][h*64+d] f16. Vt: [b][h][d][t] f16. y: [b][t][h*64+d] f16.
// Block = 4 waves = 64 q rows; 128-key LDS tiles; fixed-max softmax (exp2,
// scale folded into Q); row-sum reduced once at the end.
__global__ __launch_bounds__(256)
void attn_kernel(const _Float16* __restrict__ Qb, const _Float16* __restrict__ Kb,
                 const _Float16* __restrict__ Vt, _Float16* __restrict__ y) {
    __shared__ __align__(16) _Float16 Ks[128 * 72];     // [key][d]
    __shared__ __align__(16) _Float16 Vs[64 * 136];     // [d][key]
    __shared__ __align__(16) _Float16 Ps[4][16 * 136];  // per-wave [q][key]
    int tid = threadIdx.x;
    int w = tid >> 6, l = tid & 63;
    int lr = l & 15, lq = l >> 4;
    int blk = blockIdx.x;
    int bh = blk % BH;
    int qb = 31 - blk / BH;                // heavy q-tiles first
    int b = bh / NHEAD, h = bh % NHEAD;
    int q0 = qb * 64 + w * 16;

    const _Float16* Qp = Qb + (long)b * T_SEQ * CDIM + h * HDIM;
    const _Float16* Kg = Kb + (long)b * T_SEQ * CDIM + h * HDIM;
    const _Float16* Vg = Vt + (long)bh * HDIM * T_SEQ;

    // K staging: 128 rows x 8 col-groups; V staging: 64 rows x 16 col-groups
    int kr = tid >> 3, kc = (tid & 7) * 8;     // + j*32 rows
    int vr = tid >> 4, vc = (tid & 15) * 8;    // + j*16 rows

    const float qscale = 0.125f * 1.44269504f;
    half8 aq[2];
    #pragma unroll
    for (int kk = 0; kk < 2; ++kk) {
        aq[kk] = *(const half8*)&Qp[(long)(q0 + lr) * CDIM + kk * 32 + lq * 8];
        #pragma unroll
        for (int j = 0; j < 8; ++j) aq[kk][j] = f2h((float)aq[kk][j] * qscale);
    }

    int nk = (qb + 2) >> 1;   // number of 128-key tiles covering [0, qb*64+64)

    half8 Kr[4], Vr[4];
    #pragma unroll
    for (int j = 0; j < 4; ++j) {
        Kr[j] = *(const half8*)&Kg[(long)(j * 32 + kr) * CDIM + kc];
        Vr[j] = *(const half8*)&Vg[(long)(j * 16 + vr) * T_SEQ + vc];
    }

    float psum[4] = {0.f, 0.f, 0.f, 0.f};
    floatx4 acc[4] = {};

    for (int kt = 0; kt < nk; ++kt) {
        int kbase = kt * 128;
        #pragma unroll
        for (int j = 0; j < 4; ++j) {
            *(half8*)&Ks[(j * 32 + kr) * 72 + kc] = Kr[j];
            *(half8*)&Vs[(j * 16 + vr) * 136 + vc] = Vr[j];
        }
        __syncthreads();
        if (kt + 1 < nk) {
            int nb = kbase + 128;
            #pragma unroll
            for (int j = 0; j < 4; ++j) {
                Kr[j] = *(const half8*)&Kg[(long)(nb + j * 32 + kr) * CDIM + kc];
                Vr[j] = *(const half8*)&Vg[(long)(j * 16 + vr) * T_SEQ + nb + vc];
            }
        }

        // S = Q K^T : 16 q x 128 k, 8 subtiles
        floatx4 sacc[8];
        #pragma unroll
        for (int s = 0; s < 8; ++s) sacc[s] = floatx4{0.f, 0.f, 0.f, 0.f};
        #pragma unroll
        for (int s = 0; s < 8; ++s)
            #pragma unroll
            for (int kh = 0; kh < 2; ++kh) {
                half8 bk = *(const half8*)&Ks[(s * 16 + lr) * 72 + kh * 32 + lq * 8];
                sacc[s] = __builtin_amdgcn_mfma_f32_16x16x32_f16(aq[kh], bk, sacc[s], 0, 0, 0);
            }

        if (kt == nk - 1) {   // tile containing the diagonal (and possibly beyond)
            #pragma unroll
            for (int r = 0; r < 4; ++r) {
                int row = q0 + lq * 4 + r;
                #pragma unroll
                for (int s = 0; s < 8; ++s) {
                    float p = (kbase + s * 16 + lr > row) ? 0.f
                              : __builtin_amdgcn_exp2f(sacc[s][r]);
                    psum[r] += p;
                    Ps[w][(lq * 4 + r) * 136 + s * 16 + lr] = f2h(p);
                }
            }
        } else {
            #pragma unroll
            for (int r = 0; r < 4; ++r) {
                #pragma unroll
                for (int s = 0; s < 8; ++s) {
                    float p = __builtin_amdgcn_exp2f(sacc[s][r]);
                    psum[r] += p;
                    Ps[w][(lq * 4 + r) * 136 + s * 16 + lr] = f2h(p);
                }
            }
        }

        half8 ap[4];
        #pragma unroll
        for (int kk = 0; kk < 4; ++kk)
            ap[kk] = *(const half8*)&Ps[w][lr * 136 + kk * 32 + lq * 8];
        #pragma unroll
        for (int n = 0; n < 4; ++n) {
            #pragma unroll
            for (int kk = 0; kk < 4; ++kk) {
                half8 bv = *(const half8*)&Vs[(n * 16 + lr) * 136 + kk * 32 + lq * 8];
                acc[n] = __builtin_amdgcn_mfma_f32_16x16x32_f16(ap[kk], bv, acc[n], 0, 0, 0);
            }
        }
        __syncthreads();
    }

    float l_i[4];
    #pragma unroll
    for (int r = 0; r < 4; ++r) {
        float s = psum[r];
        #pragma unroll
        for (int off = 1; off < 16; off <<= 1)
            s += __shfl_xor(s, off, 64);
        l_i[r] = s;
    }

    #pragma unroll
    for (int n = 0; n < 4; ++n)
        #pragma unroll
        for (int r = 0; r < 4; ++r) {
            int row = q0 + lq * 4 + r;
            float v = acc[n][r] / l_i[r];
            y[((long)(b * T_SEQ) + row) * CDIM + h * HDIM + n * 16 + lr] = f2h(v);
        }
}

extern "C" void kernel_launch(void* const* d_in, const int* in_sizes, int n_in,
                              void* d_out, int out_size, void* d_ws, size_t ws_size,
                              hipStream_t stream) {
    const float* x      = (const float*)d_in[0];
    const float* w_attn = (const float*)d_in[1];
    const float* b_attn = (const float*)d_in[2];
    const float* w_proj = (const float*)d_in[3];
    const float* b_proj = (const float*)d_in[4];
    float* out = (float*)d_out;

    char* ws = (char*)d_ws;
    _Float16* xb  = (_Float16*)(ws);                // 6,291,456
    _Float16* wTa = (_Float16*)(ws + 6291456);      // 3,538,944
    _Float16* wTp = (_Float16*)(ws + 9830400);      // 1,179,648
    _Float16* Qb  = (_Float16*)(ws + 11010048);     // 6,291,456
    _Float16* Kb  = (_Float16*)(ws + 17301504);     // 6,291,456
    _Float16* Vt  = (_Float16*)(ws + 23592960);     // 6,291,456
    _Float16* yb  = (_Float16*)(ws + 29884416);     // 6,291,456

    prologue<<<4352, 256, 0, stream>>>(x, w_attn, w_proj, xb, wTa, wTp);

    gemm_qkv<<<dim3(BT / 128, C3 / 64), 256, 0, stream>>>(xb, wTa, b_attn, Qb, Kb, Vt);

    attn_kernel<<<BH * (T_SEQ / 64), 256, 0, stream>>>(Qb, Kb, Vt, yb);

    gemm_proj<<<dim3(BT / 64, CDIM / 128), 256, 0, stream>>>(yb, wTp, b_proj, out);
}

// Round 7
// 143.727 us; speedup vs baseline: 1.1347x; 1.0619x over previous
//
#include <hip/hip_runtime.h>
#include <hip/hip_bf16.h>

// B=2, T=2048, C=768, H=12, D=64. 3C=2304. BT=4096.
// prologue (cast + weight transposes); QKV GEMM 128x96 BK=64 reg-prefetch ->
// Q,K row-major + V transposed [b][h][d][t]; causal flash attention with
// 128-key LDS tiles, fixed-max softmax, reg-prefetch, rank-paired scheduling;
// proj GEMM 64x96 BK=64.

using half4   = __attribute__((ext_vector_type(4))) _Float16;
using half8   = __attribute__((ext_vector_type(8))) _Float16;
using floatx4 = __attribute__((ext_vector_type(4))) float;

#define T_SEQ 2048
#define NHEAD 12
#define HDIM 64
#define C3 2304
#define CDIM 768
#define BT 4096
#define BH 24

static __device__ inline _Float16 f2h(float f) { return (_Float16)f; }

// ---------------- fused prologue: weight transposes + x cast ----------------
__global__ __launch_bounds__(256)
void prologue(const float* __restrict__ x, const float* __restrict__ wa,
              const float* __restrict__ wp, _Float16* __restrict__ xb,
              _Float16* __restrict__ wTa, _Float16* __restrict__ wTp) {
    __shared__ float tile[32][33];
    int blk = blockIdx.x, tid = threadIdx.x;
    if (blk < 2304) {
        const float* w; _Float16* wT; int K, N, bx, by;
        if (blk < 1728) { w = wa; wT = wTa; K = CDIM; N = C3; bx = blk % 72; by = blk / 72; }
        else { int b2 = blk - 1728; w = wp; wT = wTp; K = CDIM; N = CDIM; bx = b2 % 24; by = b2 / 24; }
        int tx = tid & 31, ty = tid >> 5;
        #pragma unroll
        for (int j = 0; j < 32; j += 8) {
            int k = by * 32 + ty + j, n = bx * 32 + tx;
            tile[ty + j][tx] = w[(long)k * N + n];
        }
        __syncthreads();
        #pragma unroll
        for (int j = 0; j < 32; j += 8) {
            int nO = bx * 32 + ty + j, kO = by * 32 + tx;
            wT[(long)nO * K + kO] = f2h(tile[tx][ty + j]);
        }
    } else {
        int b2 = blk - 2304;
        long base = (long)b2 * 1536;
        #pragma unroll
        for (int j = 0; j < 6; ++j) {
            long i = base + j * 256 + tid;
            xb[i] = f2h(x[i]);
        }
    }
}

// ---------------- QKV GEMM: 128x96 tile, BK=64, register-prefetch ------------
// A[4096][768] f16, Bt[2304][768] f16. Writes Q,K row-major; V -> Vt[b][h][d][t].
// Grid 32x24 = 768 blocks = 3/CU exact.
__global__ __launch_bounds__(256)
void gemm_qkv(const _Float16* __restrict__ A, const _Float16* __restrict__ Bt,
              const float* __restrict__ bias,
              _Float16* __restrict__ Qb, _Float16* __restrict__ Kb,
              _Float16* __restrict__ Vt) {
    __shared__ __align__(16) _Float16 As[128 * 72];
    __shared__ __align__(16) _Float16 Bs[96 * 72];
    const int K = CDIM;
    int tid = threadIdx.x;
    int m0 = blockIdx.x * 128, n0 = blockIdx.y * 96;
    int w = tid >> 6, l = tid & 63;
    int wm = (w >> 1) * 64, wn = (w & 1) * 48;
    int lr = l & 15, lq = l >> 4;

    int rs = tid >> 3, cs = (tid & 7) * 8;   // row step 32 per j

    floatx4 acc[4][3] = {};

    half8 Ar[4], Br[3];
    #pragma unroll
    for (int j = 0; j < 4; ++j)
        Ar[j] = *(const half8*)&A[(long)(m0 + j * 32 + rs) * K + cs];
    #pragma unroll
    for (int j = 0; j < 3; ++j)
        Br[j] = *(const half8*)&Bt[(long)(n0 + j * 32 + rs) * K + cs];

    for (int kb = 0; kb < K; kb += 64) {
        #pragma unroll
        for (int j = 0; j < 4; ++j)
            *(half8*)&As[(j * 32 + rs) * 72 + cs] = Ar[j];
        #pragma unroll
        for (int j = 0; j < 3; ++j)
            *(half8*)&Bs[(j * 32 + rs) * 72 + cs] = Br[j];
        __syncthreads();
        if (kb + 64 < K) {
            #pragma unroll
            for (int j = 0; j < 4; ++j)
                Ar[j] = *(const half8*)&A[(long)(m0 + j * 32 + rs) * K + kb + 64 + cs];
            #pragma unroll
            for (int j = 0; j < 3; ++j)
                Br[j] = *(const half8*)&Bt[(long)(n0 + j * 32 + rs) * K + kb + 64 + cs];
        }
        #pragma unroll
        for (int kh = 0; kh < 2; ++kh) {
            half8 af[4], bf[3];
            #pragma unroll
            for (int i = 0; i < 4; ++i)
                af[i] = *(const half8*)&As[(wm + i * 16 + lr) * 72 + kh * 32 + lq * 8];
            #pragma unroll
            for (int i = 0; i < 3; ++i)
                bf[i] = *(const half8*)&Bs[(wn + i * 16 + lr) * 72 + kh * 32 + lq * 8];
            #pragma unroll
            for (int mi = 0; mi < 4; ++mi)
                #pragma unroll
                for (int ni = 0; ni < 3; ++ni)
                    acc[mi][ni] = __builtin_amdgcn_mfma_f32_16x16x32_f16(af[mi], bf[ni], acc[mi][ni], 0, 0, 0);
        }
        __syncthreads();
    }

    int region = n0 / CDIM;   // by 0-7 Q, 8-15 K, 16-23 V
    if (region < 2) {
        _Float16* O = region ? Kb : Qb;
        int nc0 = n0 - region * CDIM + wn;
        #pragma unroll
        for (int mi = 0; mi < 4; ++mi)
            #pragma unroll
            for (int ni = 0; ni < 3; ++ni) {
                int col = nc0 + ni * 16 + lr;
                float bsc = bias[region * CDIM + col];
                #pragma unroll
                for (int r = 0; r < 4; ++r) {
                    int row = m0 + wm + mi * 16 + lq * 4 + r;
                    O[(long)row * CDIM + col] = f2h(acc[mi][ni][r] + bsc);
                }
            }
    } else {
        #pragma unroll
        for (int mi = 0; mi < 4; ++mi)
            #pragma unroll
            for (int ni = 0; ni < 3; ++ni) {
                int cv = n0 - 2 * CDIM + wn + ni * 16 + lr;    // 0..767
                float bsc = bias[2 * CDIM + cv];
                int h = cv >> 6, d = cv & 63;
                int t0 = m0 + wm + mi * 16 + lq * 4;
                int bb = t0 >> 11, t = t0 & 2047;
                half4 hv;
                #pragma unroll
                for (int r = 0; r < 4; ++r) hv[r] = f2h(acc[mi][ni][r] + bsc);
                *(half4*)&Vt[(((long)bb * NHEAD + h) * HDIM + d) * T_SEQ + t] = hv;
            }
    }
}

// ---------------- proj GEMM: 64x96 tile, BK=64, reg-prefetch, fp32 out -------
// Grid 64x8 = 512 blocks = 2/CU exact.
__global__ __launch_bounds__(256)
void gemm_proj(const _Float16* __restrict__ A, const _Float16* __restrict__ Bt,
               const float* __restrict__ bias, float* __restrict__ Cout) {
    __shared__ __align__(16) _Float16 As[64 * 72];
    __shared__ __align__(16) _Float16 Bs[96 * 72];
    const int K = CDIM, N = CDIM;
    int tid = threadIdx.x;
    int m0 = blockIdx.x * 64, n0 = blockIdx.y * 96;
    int w = tid >> 6, l = tid & 63;
    int wm = (w >> 1) * 32, wn = (w & 1) * 48;
    int lr = l & 15, lq = l >> 4;

    int rs = tid >> 3, cs = (tid & 7) * 8;

    floatx4 acc[2][3] = {};

    half8 Ar[2], Br[3];
    #pragma unroll
    for (int j = 0; j < 2; ++j)
        Ar[j] = *(const half8*)&A[(long)(m0 + j * 32 + rs) * K + cs];
    #pragma unroll
    for (int j = 0; j < 3; ++j)
        Br[j] = *(const half8*)&Bt[(long)(n0 + j * 32 + rs) * K + cs];

    for (int kb = 0; kb < K; kb += 64) {
        #pragma unroll
        for (int j = 0; j < 2; ++j)
            *(half8*)&As[(j * 32 + rs) * 72 + cs] = Ar[j];
        #pragma unroll
        for (int j = 0; j < 3; ++j)
            *(half8*)&Bs[(j * 32 + rs) * 72 + cs] = Br[j];
        __syncthreads();
        if (kb + 64 < K) {
            #pragma unroll
            for (int j = 0; j < 2; ++j)
                Ar[j] = *(const half8*)&A[(long)(m0 + j * 32 + rs) * K + kb + 64 + cs];
            #pragma unroll
            for (int j = 0; j < 3; ++j)
                Br[j] = *(const half8*)&Bt[(long)(n0 + j * 32 + rs) * K + kb + 64 + cs];
        }
        #pragma unroll
        for (int kh = 0; kh < 2; ++kh) {
            half8 af[2], bf[3];
            #pragma unroll
            for (int i = 0; i < 2; ++i)
                af[i] = *(const half8*)&As[(wm + i * 16 + lr) * 72 + kh * 32 + lq * 8];
            #pragma unroll
            for (int i = 0; i < 3; ++i)
                bf[i] = *(const half8*)&Bs[(wn + i * 16 + lr) * 72 + kh * 32 + lq * 8];
            #pragma unroll
            for (int mi = 0; mi < 2; ++mi)
                #pragma unroll
                for (int ni = 0; ni < 3; ++ni)
                    acc[mi][ni] = __builtin_amdgcn_mfma_f32_16x16x32_f16(af[mi], bf[ni], acc[mi][ni], 0, 0, 0);
        }
        __syncthreads();
    }
    #pragma unroll
    for (int mi = 0; mi < 2; ++mi)
        #pragma unroll
        for (int ni = 0; ni < 3; ++ni) {
            int col = n0 + wn + ni * 16 + lr;
            float b = bias[col];
            #pragma unroll
            for (int r = 0; r < 4; ++r) {
                int row = m0 + wm + mi * 16 + lq * 4 + r;
                Cout[(long)row * N + col] = acc[mi][ni][r] + b;
            }
        }
}

// ---------------- causal flash attention, 128-key tiles, rank-paired ---------
// Q,K: [b][t][h*64+d] f16. Vt: [b][h][d][t] f16. y: [b][t][h*64+d] f16.
// Work item rank r (heavy-first): qb = 31 - r/24, bh = r%24.
// Launch order pairs heavy+light per CU: round0->c, round1->767-c, round2->256+c,
// so each CU's first two blocks sum to exactly 33 work units.
__global__ __launch_bounds__(256)
void attn_kernel(const _Float16* __restrict__ Qb, const _Float16* __restrict__ Kb,
                 const _Float16* __restrict__ Vt, _Float16* __restrict__ y) {
    __shared__ __align__(16) _Float16 Ks[128 * 72];     // [key][d]
    __shared__ __align__(16) _Float16 Vs[64 * 136];     // [d][key]
    __shared__ __align__(16) _Float16 Ps[4][16 * 136];  // per-wave [q][key]
    int tid = threadIdx.x;
    int w = tid >> 6, l = tid & 63;
    int lr = l & 15, lq = l >> 4;
    int i = blockIdx.x;
    int round = i >> 8, c = i & 255;
    int r_ = (round == 0) ? c : (round == 1 ? 767 - c : 256 + c);
    int qb = 31 - r_ / 24;
    int bh = r_ % 24;
    int b = bh / NHEAD, h = bh % NHEAD;
    int q0 = qb * 64 + w * 16;

    const _Float16* Qp = Qb + (long)b * T_SEQ * CDIM + h * HDIM;
    const _Float16* Kg = Kb + (long)b * T_SEQ * CDIM + h * HDIM;
    const _Float16* Vg = Vt + (long)bh * HDIM * T_SEQ;

    int kr = tid >> 3, kc = (tid & 7) * 8;     // K staging: + j*32 rows
    int vr = tid >> 4, vc = (tid & 15) * 8;    // V staging: + j*16 rows

    const float qscale = 0.125f * 1.44269504f;
    half8 aq[2];
    #pragma unroll
    for (int kk = 0; kk < 2; ++kk) {
        aq[kk] = *(const half8*)&Qp[(long)(q0 + lr) * CDIM + kk * 32 + lq * 8];
        #pragma unroll
        for (int j = 0; j < 8; ++j) aq[kk][j] = f2h((float)aq[kk][j] * qscale);
    }

    int nk = (qb + 2) >> 1;   // 128-key tiles covering [0, qb*64+64)

    half8 Kr[4], Vr[4];
    #pragma unroll
    for (int j = 0; j < 4; ++j) {
        Kr[j] = *(const half8*)&Kg[(long)(j * 32 + kr) * CDIM + kc];
        Vr[j] = *(const half8*)&Vg[(long)(j * 16 + vr) * T_SEQ + vc];
    }

    float psum[4] = {0.f, 0.f, 0.f, 0.f};
    floatx4 acc[4] = {};

    for (int kt = 0; kt < nk; ++kt) {
        int kbase = kt * 128;
        #pragma unroll
        for (int j = 0; j < 4; ++j) {
            *(half8*)&Ks[(j * 32 + kr) * 72 + kc] = Kr[j];
            *(half8*)&Vs[(j * 16 + vr) * 136 + vc] = Vr[j];
        }
        __syncthreads();
        if (kt + 1 < nk) {
            int nb = kbase + 128;
            #pragma unroll
            for (int j = 0; j < 4; ++j) {
                Kr[j] = *(const half8*)&Kg[(long)(nb + j * 32 + kr) * CDIM + kc];
                Vr[j] = *(const half8*)&Vg[(long)(j * 16 + vr) * T_SEQ + nb + vc];
            }
        }

        floatx4 sacc[8];
        #pragma unroll
        for (int s = 0; s < 8; ++s) sacc[s] = floatx4{0.f, 0.f, 0.f, 0.f};
        #pragma unroll
        for (int s = 0; s < 8; ++s)
            #pragma unroll
            for (int kh = 0; kh < 2; ++kh) {
                half8 bk = *(const half8*)&Ks[(s * 16 + lr) * 72 + kh * 32 + lq * 8];
                sacc[s] = __builtin_amdgcn_mfma_f32_16x16x32_f16(aq[kh], bk, sacc[s], 0, 0, 0);
            }

        if (kt == nk - 1) {   // tile containing the diagonal
            #pragma unroll
            for (int r = 0; r < 4; ++r) {
                int row = q0 + lq * 4 + r;
                #pragma unroll
                for (int s = 0; s < 8; ++s) {
                    float p = (kbase + s * 16 + lr > row) ? 0.f
                              : __builtin_amdgcn_exp2f(sacc[s][r]);
                    psum[r] += p;
                    Ps[w][(lq * 4 + r) * 136 + s * 16 + lr] = f2h(p);
                }
            }
        } else {
            #pragma unroll
            for (int r = 0; r < 4; ++r) {
                #pragma unroll
                for (int s = 0; s < 8; ++s) {
                    float p = __builtin_amdgcn_exp2f(sacc[s][r]);
                    psum[r] += p;
                    Ps[w][(lq * 4 + r) * 136 + s * 16 + lr] = f2h(p);
                }
            }
        }

        half8 ap[4];
        #pragma unroll
        for (int kk = 0; kk < 4; ++kk)
            ap[kk] = *(const half8*)&Ps[w][lr * 136 + kk * 32 + lq * 8];
        #pragma unroll
        for (int n = 0; n < 4; ++n) {
            #pragma unroll
            for (int kk = 0; kk < 4; ++kk) {
                half8 bv = *(const half8*)&Vs[(n * 16 + lr) * 136 + kk * 32 + lq * 8];
                acc[n] = __builtin_amdgcn_mfma_f32_16x16x32_f16(ap[kk], bv, acc[n], 0, 0, 0);
            }
        }
        __syncthreads();
    }

    float l_i[4];
    #pragma unroll
    for (int r = 0; r < 4; ++r) {
        float s = psum[r];
        #pragma unroll
        for (int off = 1; off < 16; off <<= 1)
            s += __shfl_xor(s, off, 64);
        l_i[r] = s;
    }

    #pragma unroll
    for (int n = 0; n < 4; ++n)
        #pragma unroll
        for (int r = 0; r < 4; ++r) {
            int row = q0 + lq * 4 + r;
            float v = acc[n][r] / l_i[r];
            y[((long)(b * T_SEQ) + row) * CDIM + h * HDIM + n * 16 + lr] = f2h(v);
        }
}

extern "C" void kernel_launch(void* const* d_in, const int* in_sizes, int n_in,
                              void* d_out, int out_size, void* d_ws, size_t ws_size,
                              hipStream_t stream) {
    const float* x      = (const float*)d_in[0];
    const float* w_attn = (const float*)d_in[1];
    const float* b_attn = (const float*)d_in[2];
    const float* w_proj = (const float*)d_in[3];
    const float* b_proj = (const float*)d_in[4];
    float* out = (float*)d_out;

    char* ws = (char*)d_ws;
    _Float16* xb  = (_Float16*)(ws);                // 6,291,456
    _Float16* wTa = (_Float16*)(ws + 6291456);      // 3,538,944
    _Float16* wTp = (_Float16*)(ws + 9830400);      // 1,179,648
    _Float16* Qb  = (_Float16*)(ws + 11010048);     // 6,291,456
    _Float16* Kb  = (_Float16*)(ws + 17301504);     // 6,291,456
    _Float16* Vt  = (_Float16*)(ws + 23592960);     // 6,291,456
    _Float16* yb  = (_Float16*)(ws + 29884416);     // 6,291,456

    prologue<<<4352, 256, 0, stream>>>(x, w_attn, w_proj, xb, wTa, wTp);

    gemm_qkv<<<dim3(BT / 128, C3 / 96), 256, 0, stream>>>(xb, wTa, b_attn, Qb, Kb, Vt);

    attn_kernel<<<BH * (T_SEQ / 64), 256, 0, stream>>>(Qb, Kb, Vt, yb);

    gemm_proj<<<dim3(BT / 64, CDIM / 96), 256, 0, stream>>>(yb, wTp, b_proj, out);
}

// Round 8
// 139.076 us; speedup vs baseline: 1.1727x; 1.0334x over previous
//
#include <hip/hip_runtime.h>
#include <hip/hip_bf16.h>

// B=2, T=2048, C=768, H=12, D=64. 3C=2304. BT=4096.
// prologue (cast + weight transposes); QKV GEMM 128x96 BK=64 reg-prefetch ->
// Q,K row-major + V transposed [b][h][d][t]; causal flash attention computing
// S^T (swapped MFMA operands) so P stores are packed b64, 128-key LDS tiles,
// fixed-max softmax, reg-prefetch, rank-paired scheduling; proj GEMM 64x96.

using half4   = __attribute__((ext_vector_type(4))) _Float16;
using half8   = __attribute__((ext_vector_type(8))) _Float16;
using floatx4 = __attribute__((ext_vector_type(4))) float;

#define T_SEQ 2048
#define NHEAD 12
#define HDIM 64
#define C3 2304
#define CDIM 768
#define BT 4096
#define BH 24

static __device__ inline _Float16 f2h(float f) { return (_Float16)f; }

// ---------------- fused prologue: weight transposes + x cast ----------------
// blocks [0,1728): wTa; [1728,2304): wTp; [2304,3072): x cast (float4 vectorized)
__global__ __launch_bounds__(256)
void prologue(const float* __restrict__ x, const float* __restrict__ wa,
              const float* __restrict__ wp, _Float16* __restrict__ xb,
              _Float16* __restrict__ wTa, _Float16* __restrict__ wTp) {
    __shared__ float tile[32][33];
    int blk = blockIdx.x, tid = threadIdx.x;
    if (blk < 2304) {
        const float* w; _Float16* wT; int K, N, bx, by;
        if (blk < 1728) { w = wa; wT = wTa; K = CDIM; N = C3; bx = blk % 72; by = blk / 72; }
        else { int b2 = blk - 1728; w = wp; wT = wTp; K = CDIM; N = CDIM; bx = b2 % 24; by = b2 / 24; }
        int tx = tid & 31, ty = tid >> 5;
        #pragma unroll
        for (int j = 0; j < 32; j += 8) {
            int k = by * 32 + ty + j, n = bx * 32 + tx;
            tile[ty + j][tx] = w[(long)k * N + n];
        }
        __syncthreads();
        #pragma unroll
        for (int j = 0; j < 32; j += 8) {
            int nO = bx * 32 + ty + j, kO = by * 32 + tx;
            wT[(long)nO * K + kO] = f2h(tile[tx][ty + j]);
        }
    } else {
        int b2 = blk - 2304;                 // 768 blocks x 4096 elems
        long e0 = (long)b2 * 4096 + tid * 16;
        floatx4 f0 = *(const floatx4*)&x[e0];
        floatx4 f1 = *(const floatx4*)&x[e0 + 4];
        floatx4 f2 = *(const floatx4*)&x[e0 + 8];
        floatx4 f3 = *(const floatx4*)&x[e0 + 12];
        half8 h0, h1;
        #pragma unroll
        for (int j = 0; j < 4; ++j) {
            h0[j] = f2h(f0[j]); h0[4 + j] = f2h(f1[j]);
            h1[j] = f2h(f2[j]); h1[4 + j] = f2h(f3[j]);
        }
        *(half8*)&xb[e0] = h0;
        *(half8*)&xb[e0 + 8] = h1;
    }
}

// ---------------- QKV GEMM: 128x96 tile, BK=64, register-prefetch ------------
// Grid 32x24 = 768 blocks = 3/CU exact.
__global__ __launch_bounds__(256)
void gemm_qkv(const _Float16* __restrict__ A, const _Float16* __restrict__ Bt,
              const float* __restrict__ bias,
              _Float16* __restrict__ Qb, _Float16* __restrict__ Kb,
              _Float16* __restrict__ Vt) {
    __shared__ __align__(16) _Float16 As[128 * 72];
    __shared__ __align__(16) _Float16 Bs[96 * 72];
    const int K = CDIM;
    int tid = threadIdx.x;
    int m0 = blockIdx.x * 128, n0 = blockIdx.y * 96;
    int w = tid >> 6, l = tid & 63;
    int wm = (w >> 1) * 64, wn = (w & 1) * 48;
    int lr = l & 15, lq = l >> 4;

    int rs = tid >> 3, cs = (tid & 7) * 8;   // row step 32 per j

    floatx4 acc[4][3] = {};

    half8 Ar[4], Br[3];
    #pragma unroll
    for (int j = 0; j < 4; ++j)
        Ar[j] = *(const half8*)&A[(long)(m0 + j * 32 + rs) * K + cs];
    #pragma unroll
    for (int j = 0; j < 3; ++j)
        Br[j] = *(const half8*)&Bt[(long)(n0 + j * 32 + rs) * K + cs];

    for (int kb = 0; kb < K; kb += 64) {
        #pragma unroll
        for (int j = 0; j < 4; ++j)
            *(half8*)&As[(j * 32 + rs) * 72 + cs] = Ar[j];
        #pragma unroll
        for (int j = 0; j < 3; ++j)
            *(half8*)&Bs[(j * 32 + rs) * 72 + cs] = Br[j];
        __syncthreads();
        if (kb + 64 < K) {
            #pragma unroll
            for (int j = 0; j < 4; ++j)
                Ar[j] = *(const half8*)&A[(long)(m0 + j * 32 + rs) * K + kb + 64 + cs];
            #pragma unroll
            for (int j = 0; j < 3; ++j)
                Br[j] = *(const half8*)&Bt[(long)(n0 + j * 32 + rs) * K + kb + 64 + cs];
        }
        #pragma unroll
        for (int kh = 0; kh < 2; ++kh) {
            half8 af[4], bf[3];
            #pragma unroll
            for (int i = 0; i < 4; ++i)
                af[i] = *(const half8*)&As[(wm + i * 16 + lr) * 72 + kh * 32 + lq * 8];
            #pragma unroll
            for (int i = 0; i < 3; ++i)
                bf[i] = *(const half8*)&Bs[(wn + i * 16 + lr) * 72 + kh * 32 + lq * 8];
            #pragma unroll
            for (int mi = 0; mi < 4; ++mi)
                #pragma unroll
                for (int ni = 0; ni < 3; ++ni)
                    acc[mi][ni] = __builtin_amdgcn_mfma_f32_16x16x32_f16(af[mi], bf[ni], acc[mi][ni], 0, 0, 0);
        }
        __syncthreads();
    }

    int region = n0 / CDIM;
    if (region < 2) {
        _Float16* O = region ? Kb : Qb;
        int nc0 = n0 - region * CDIM + wn;
        #pragma unroll
        for (int mi = 0; mi < 4; ++mi)
            #pragma unroll
            for (int ni = 0; ni < 3; ++ni) {
                int col = nc0 + ni * 16 + lr;
                float bsc = bias[region * CDIM + col];
                #pragma unroll
                for (int r = 0; r < 4; ++r) {
                    int row = m0 + wm + mi * 16 + lq * 4 + r;
                    O[(long)row * CDIM + col] = f2h(acc[mi][ni][r] + bsc);
                }
            }
    } else {
        #pragma unroll
        for (int mi = 0; mi < 4; ++mi)
            #pragma unroll
            for (int ni = 0; ni < 3; ++ni) {
                int cv = n0 - 2 * CDIM + wn + ni * 16 + lr;    // 0..767
                float bsc = bias[2 * CDIM + cv];
                int h = cv >> 6, d = cv & 63;
                int t0 = m0 + wm + mi * 16 + lq * 4;
                int bb = t0 >> 11, t = t0 & 2047;
                half4 hv;
                #pragma unroll
                for (int r = 0; r < 4; ++r) hv[r] = f2h(acc[mi][ni][r] + bsc);
                *(half4*)&Vt[(((long)bb * NHEAD + h) * HDIM + d) * T_SEQ + t] = hv;
            }
    }
}

// ---------------- proj GEMM: 64x96 tile, BK=64, reg-prefetch, fp32 out -------
// Grid 64x8 = 512 blocks = 2/CU exact.
__global__ __launch_bounds__(256)
void gemm_proj(const _Float16* __restrict__ A, const _Float16* __restrict__ Bt,
               const float* __restrict__ bias, float* __restrict__ Cout) {
    __shared__ __align__(16) _Float16 As[64 * 72];
    __shared__ __align__(16) _Float16 Bs[96 * 72];
    const int K = CDIM, N = CDIM;
    int tid = threadIdx.x;
    int m0 = blockIdx.x * 64, n0 = blockIdx.y * 96;
    int w = tid >> 6, l = tid & 63;
    int wm = (w >> 1) * 32, wn = (w & 1) * 48;
    int lr = l & 15, lq = l >> 4;

    int rs = tid >> 3, cs = (tid & 7) * 8;

    floatx4 acc[2][3] = {};

    half8 Ar[2], Br[3];
    #pragma unroll
    for (int j = 0; j < 2; ++j)
        Ar[j] = *(const half8*)&A[(long)(m0 + j * 32 + rs) * K + cs];
    #pragma unroll
    for (int j = 0; j < 3; ++j)
        Br[j] = *(const half8*)&Bt[(long)(n0 + j * 32 + rs) * K + cs];

    for (int kb = 0; kb < K; kb += 64) {
        #pragma unroll
        for (int j = 0; j < 2; ++j)
            *(half8*)&As[(j * 32 + rs) * 72 + cs] = Ar[j];
        #pragma unroll
        for (int j = 0; j < 3; ++j)
            *(half8*)&Bs[(j * 32 + rs) * 72 + cs] = Br[j];
        __syncthreads();
        if (kb + 64 < K) {
            #pragma unroll
            for (int j = 0; j < 2; ++j)
                Ar[j] = *(const half8*)&A[(long)(m0 + j * 32 + rs) * K + kb + 64 + cs];
            #pragma unroll
            for (int j = 0; j < 3; ++j)
                Br[j] = *(const half8*)&Bt[(long)(n0 + j * 32 + rs) * K + kb + 64 + cs];
        }
        #pragma unroll
        for (int kh = 0; kh < 2; ++kh) {
            half8 af[2], bf[3];
            #pragma unroll
            for (int i = 0; i < 2; ++i)
                af[i] = *(const half8*)&As[(wm + i * 16 + lr) * 72 + kh * 32 + lq * 8];
            #pragma unroll
            for (int i = 0; i < 3; ++i)
                bf[i] = *(const half8*)&Bs[(wn + i * 16 + lr) * 72 + kh * 32 + lq * 8];
            #pragma unroll
            for (int mi = 0; mi < 2; ++mi)
                #pragma unroll
                for (int ni = 0; ni < 3; ++ni)
                    acc[mi][ni] = __builtin_amdgcn_mfma_f32_16x16x32_f16(af[mi], bf[ni], acc[mi][ni], 0, 0, 0);
        }
        __syncthreads();
    }
    #pragma unroll
    for (int mi = 0; mi < 2; ++mi)
        #pragma unroll
        for (int ni = 0; ni < 3; ++ni) {
            int col = n0 + wn + ni * 16 + lr;
            float b = bias[col];
            #pragma unroll
            for (int r = 0; r < 4; ++r) {
                int row = m0 + wm + mi * 16 + lq * 4 + r;
                Cout[(long)row * N + col] = acc[mi][ni][r] + b;
            }
        }
}

// ---------------- causal flash attention: S^T form, packed P stores ----------
// Q,K: [b][t][h*64+d] f16. Vt: [b][h][d][t] f16. y: [b][t][h*64+d] f16.
// S^T = K·Q^T via swapped MFMA operands (A/B fragment lane maps are identical),
// so lane holds 4 consecutive keys for fixed q -> P stored with ds_write_b64
// into Ps[q][key]; PV A-fragments read back as ds_read_b128. Fixed-max softmax,
// per-lane scalar psum, 2-shuffle reduce + shfl distribution at the end.
__global__ __launch_bounds__(256)
void attn_kernel(const _Float16* __restrict__ Qb, const _Float16* __restrict__ Kb,
                 const _Float16* __restrict__ Vt, _Float16* __restrict__ y) {
    __shared__ __align__(16) _Float16 Ks[128 * 72];     // [key][d]
    __shared__ __align__(16) _Float16 Vs[64 * 136];     // [d][key]
    __shared__ __align__(16) _Float16 Ps[4][16 * 136];  // per-wave [q][key]
    int tid = threadIdx.x;
    int w = tid >> 6, l = tid & 63;
    int lr = l & 15, lq = l >> 4;
    int i = blockIdx.x;
    int round = i >> 8, c = i & 255;
    int r_ = (round == 0) ? c : (round == 1 ? 767 - c : 256 + c);
    int qb = 31 - r_ / 24;
    int bh = r_ % 24;
    int b = bh / NHEAD, h = bh % NHEAD;
    int q0 = qb * 64 + w * 16;

    const _Float16* Qp = Qb + (long)b * T_SEQ * CDIM + h * HDIM;
    const _Float16* Kg = Kb + (long)b * T_SEQ * CDIM + h * HDIM;
    const _Float16* Vg = Vt + (long)bh * HDIM * T_SEQ;

    int kr = tid >> 3, kc = (tid & 7) * 8;     // K staging: + j*32 rows
    int vr = tid >> 4, vc = (tid & 15) * 8;    // V staging: + j*16 rows

    const float qscale = 0.125f * 1.44269504f;
    half8 aq[2];
    #pragma unroll
    for (int kk = 0; kk < 2; ++kk) {
        aq[kk] = *(const half8*)&Qp[(long)(q0 + lr) * CDIM + kk * 32 + lq * 8];
        #pragma unroll
        for (int j = 0; j < 8; ++j) aq[kk][j] = f2h((float)aq[kk][j] * qscale);
    }

    int nk = (qb + 2) >> 1;   // 128-key tiles covering [0, qb*64+64)

    half8 Kr[4], Vr[4];
    #pragma unroll
    for (int j = 0; j < 4; ++j) {
        Kr[j] = *(const half8*)&Kg[(long)(j * 32 + kr) * CDIM + kc];
        Vr[j] = *(const half8*)&Vg[(long)(j * 16 + vr) * T_SEQ + vc];
    }

    float psum = 0.f;          // all values this lane produces share q = q0+lr
    floatx4 acc[4] = {};
    int qrow = q0 + lr;

    for (int kt = 0; kt < nk; ++kt) {
        int kbase = kt * 128;
        #pragma unroll
        for (int j = 0; j < 4; ++j) {
            *(half8*)&Ks[(j * 32 + kr) * 72 + kc] = Kr[j];
            *(half8*)&Vs[(j * 16 + vr) * 136 + vc] = Vr[j];
        }
        __syncthreads();
        if (kt + 1 < nk) {
            int nb = kbase + 128;
            #pragma unroll
            for (int j = 0; j < 4; ++j) {
                Kr[j] = *(const half8*)&Kg[(long)(nb + j * 32 + kr) * CDIM + kc];
                Vr[j] = *(const half8*)&Vg[(long)(j * 16 + vr) * T_SEQ + nb + vc];
            }
        }

        // S^T = K Q^T : C rows = keys (lq*4+r within 16-key subtile), cols = q (lr)
        floatx4 sacc[8];
        #pragma unroll
        for (int s = 0; s < 8; ++s) sacc[s] = floatx4{0.f, 0.f, 0.f, 0.f};
        #pragma unroll
        for (int s = 0; s < 8; ++s)
            #pragma unroll
            for (int kh = 0; kh < 2; ++kh) {
                half8 bk = *(const half8*)&Ks[(s * 16 + lr) * 72 + kh * 32 + lq * 8];
                sacc[s] = __builtin_amdgcn_mfma_f32_16x16x32_f16(bk, aq[kh], sacc[s], 0, 0, 0);
            }

        if (kt == nk - 1) {   // tile containing the diagonal
            #pragma unroll
            for (int s = 0; s < 8; ++s) {
                half4 hv;
                #pragma unroll
                for (int r = 0; r < 4; ++r) {
                    int key = kbase + s * 16 + lq * 4 + r;
                    float p = (key > qrow) ? 0.f : __builtin_amdgcn_exp2f(sacc[s][r]);
                    psum += p;
                    hv[r] = f2h(p);
                }
                *(half4*)&Ps[w][lr * 136 + s * 16 + lq * 4] = hv;
            }
        } else {
            #pragma unroll
            for (int s = 0; s < 8; ++s) {
                half4 hv;
                #pragma unroll
                for (int r = 0; r < 4; ++r) {
                    float p = __builtin_amdgcn_exp2f(sacc[s][r]);
                    psum += p;
                    hv[r] = f2h(p);
                }
                *(half4*)&Ps[w][lr * 136 + s * 16 + lq * 4] = hv;
            }
        }

        half8 ap[4];
        #pragma unroll
        for (int kk = 0; kk < 4; ++kk)
            ap[kk] = *(const half8*)&Ps[w][lr * 136 + kk * 32 + lq * 8];
        #pragma unroll
        for (int n = 0; n < 4; ++n) {
            #pragma unroll
            for (int kk = 0; kk < 4; ++kk) {
                half8 bv = *(const half8*)&Vs[(n * 16 + lr) * 136 + kk * 32 + lq * 8];
                acc[n] = __builtin_amdgcn_mfma_f32_16x16x32_f16(ap[kk], bv, acc[n], 0, 0, 0);
            }
        }
        __syncthreads();
    }

    // reduce psum over the 4 quads holding the same q (lanes lr, lr+16, lr+32, lr+48)
    float L = psum;
    L += __shfl_xor(L, 16, 64);
    L += __shfl_xor(L, 32, 64);
    // acc rows are q = q0 + lq*4 + r; fetch L from lane (lq*4+r)
    float Lr[4];
    #pragma unroll
    for (int r = 0; r < 4; ++r) Lr[r] = __shfl(L, lq * 4 + r, 64);

    #pragma unroll
    for (int n = 0; n < 4; ++n)
        #pragma unroll
        for (int r = 0; r < 4; ++r) {
            int row = q0 + lq * 4 + r;
            float v = acc[n][r] / Lr[r];
            y[((long)(b * T_SEQ) + row) * CDIM + h * HDIM + n * 16 + lr] = f2h(v);
        }
}

extern "C" void kernel_launch(void* const* d_in, const int* in_sizes, int n_in,
                              void* d_out, int out_size, void* d_ws, size_t ws_size,
                              hipStream_t stream) {
    const float* x      = (const float*)d_in[0];
    const float* w_attn = (const float*)d_in[1];
    const float* b_attn = (const float*)d_in[2];
    const float* w_proj = (const float*)d_in[3];
    const float* b_proj = (const float*)d_in[4];
    float* out = (float*)d_out;

    char* ws = (char*)d_ws;
    _Float16* xb  = (_Float16*)(ws);                // 6,291,456
    _Float16* wTa = (_Float16*)(ws + 6291456);      // 3,538,944
    _Float16* wTp = (_Float16*)(ws + 9830400);      // 1,179,648
    _Float16* Qb  = (_Float16*)(ws + 11010048);     // 6,291,456
    _Float16* Kb  = (_Float16*)(ws + 17301504);     // 6,291,456
    _Float16* Vt  = (_Float16*)(ws + 23592960);     // 6,291,456
    _Float16* yb  = (_Float16*)(ws + 29884416);     // 6,291,456

    prologue<<<3072, 256, 0, stream>>>(x, w_attn, w_proj, xb, wTa, wTp);

    gemm_qkv<<<dim3(BT / 128, C3 / 96), 256, 0, stream>>>(xb, wTa, b_attn, Qb, Kb, Vt);

    attn_kernel<<<BH * (T_SEQ / 64), 256, 0, stream>>>(Qb, Kb, Vt, yb);

    gemm_proj<<<dim3(BT / 64, CDIM / 96), 256, 0, stream>>>(yb, wTp, b_proj, out);
}